// Round 1
// baseline (79.721 us; speedup 1.0000x reference)
//
#include <hip/hip_runtime.h>
#include <hip/hip_bf16.h>

#define N_NODES 100000
#define N_EDGES 1600000
#define D_FEAT  64

// Kernel 1: offsets[n] = first edge index i with seg_ids[i] >= n.
// offsets[N_NODES] = N_EDGES falls out naturally (all ids < N_NODES).
__global__ void seg_offsets_kernel(const int* __restrict__ seg_ids,
                                   int* __restrict__ offsets) {
    int n = blockIdx.x * blockDim.x + threadIdx.x;
    if (n > N_NODES) return;
    int lo = 0, hi = N_EDGES;
    while (lo < hi) {
        int mid = (lo + hi) >> 1;
        if (seg_ids[mid] < n) lo = mid + 1; else hi = mid;
    }
    offsets[n] = lo;
}

// Kernel 2: 16 lanes per node; lane j owns float4 chunk j of the 64-float row.
// Registers accumulate over the node's contiguous edge range; single coalesced
// 256B store per node. No atomics -> deterministic.
__global__ void aggregate_kernel(const float* __restrict__ feat,
                                 const int* __restrict__ neigh_idx,
                                 const int* __restrict__ offsets,
                                 float* __restrict__ out) {
    int gid  = blockIdx.x * blockDim.x + threadIdx.x;
    int node = gid >> 4;
    int lane = gid & 15;
    if (node >= N_NODES) return;

    int s = offsets[node];
    int e = offsets[node + 1];

    float4 acc = make_float4(0.f, 0.f, 0.f, 0.f);
    for (int i = s; i < e; ++i) {
        int src = neigh_idx[i];  // same value across the 16-lane group (cache broadcast)
        const float4* row = reinterpret_cast<const float4*>(feat + (size_t)src * D_FEAT);
        float4 v = row[lane];
        acc.x += v.x; acc.y += v.y; acc.z += v.z; acc.w += v.w;
    }
    reinterpret_cast<float4*>(out + (size_t)node * D_FEAT)[lane] = acc;
}

extern "C" void kernel_launch(void* const* d_in, const int* in_sizes, int n_in,
                              void* d_out, int out_size, void* d_ws, size_t ws_size,
                              hipStream_t stream) {
    const float* features  = (const float*)d_in[0];
    const int*   neigh_idx = (const int*)d_in[1];
    const int*   seg_ids   = (const int*)d_in[2];
    float*       out       = (float*)d_out;
    int*         offsets   = (int*)d_ws;  // (N_NODES+1) * 4 bytes

    {
        int total = N_NODES + 1;
        int block = 256;
        int grid  = (total + block - 1) / block;
        seg_offsets_kernel<<<grid, block, 0, stream>>>(seg_ids, offsets);
    }
    {
        long long total = (long long)N_NODES * 16;  // 16 lanes per node
        int block = 256;
        int grid  = (int)((total + block - 1) / block);
        aggregate_kernel<<<grid, block, 0, stream>>>(features, neigh_idx, offsets, out);
    }
}